// Round 11
// baseline (87.887 us; speedup 1.0000x reference)
//
#include <hip/hip_runtime.h>

#define HALFB 0.5f
#define CAPB  0.1f

__device__ __forceinline__ float clip05(float z) {
    return fminf(fmaxf(z, -HALFB), HALFB);   // v_med3_f32
}

// 8-lane xor-reduce via DPP (pure VALU, no LDS pipe).
// 0xB1 = quad_perm xor1, 0x4E = quad_perm xor2, 0x141 = row_half_mirror
// (valid final stage: after xor1+xor2 each quad is uniform).
template <int CTRL>
__device__ __forceinline__ float dppf(float v) {
    return __int_as_float(__builtin_amdgcn_update_dpp(
        __float_as_int(v), __float_as_int(v), CTRL, 0xF, 0xF, false));
}
__device__ __forceinline__ float red8f(float v) {
    v += dppf<0xB1>(v); v += dppf<0x4E>(v); v += dppf<0x141>(v); return v;
}
__device__ __forceinline__ float min8f(float v) {
    v = fminf(v, dppf<0xB1>(v)); v = fminf(v, dppf<0x4E>(v));
    v = fminf(v, dppf<0x141>(v)); return v;
}
__device__ __forceinline__ float max8f(float v) {
    v = fmaxf(v, dppf<0xB1>(v)); v = fmaxf(v, dppf<0x4E>(v));
    v = fmaxf(v, dppf<0x141>(v)); return v;
}

// 8 lanes/row, 16 elems (4 x float4)/lane, interleaved ownership (r10 geometry,
// proven). Solver: bracketed SECANT on g(lam)=t — per-iter sweep computes only g
// (3 ops/elem; no n_act recount). On piecewise-linear g, secant from two evals
// in one segment is exact, so it converges like Newton. First step uses the true
// Newton slope n_act(0) (free from the init sweep). Final step: one n_act sweep
// at the converged lam + exact division == reference's closed form over the
// active set (identical fixed point to rounds 2-10, absmax 1.95e-3).
__global__ __launch_bounds__(256, 4) void proj_kernel(
    const float* __restrict__ x, float* __restrict__ out, int nrows)
{
    const int lane = threadIdx.x & 63;
    const int wid  = (blockIdx.x << 2) | (threadIdx.x >> 6);
    const int q    = lane & 7;                     // eighth of row
    int row = (wid << 3) | (lane >> 3);            // 8 rows per wave
    if (row >= nrows) row = nrows - 1;             // grid divides exactly

    const float4* __restrict__ px = (const float4*)x  + ((size_t)row << 5) + q;
    float4*       __restrict__ po = (float4*)out      + ((size_t)row << 5) + q;

    float4 v[4];
    #pragma unroll
    for (int j = 0; j < 4; ++j) v[j] = px[j << 3];   // stride 8 float4 = 128B

    // init sweep: s0 / n_act(0) / min / max (4-way partial trees)
    float s0a = 0.f, s0b = 0.f, s0c = 0.f, s0d = 0.f;
    float naa = 0.f, nab = 0.f, nac = 0.f, nad = 0.f;
    float mna = 3.0e38f, mnb = 3.0e38f, mxa = -3.0e38f, mxb = -3.0e38f;
    #pragma unroll
    for (int j = 0; j < 4; ++j) {
        s0a += clip05(v[j].x); s0b += clip05(v[j].y);
        s0c += clip05(v[j].z); s0d += clip05(v[j].w);
        naa += (fabsf(v[j].x) < HALFB) ? 1.f : 0.f;
        nab += (fabsf(v[j].y) < HALFB) ? 1.f : 0.f;
        nac += (fabsf(v[j].z) < HALFB) ? 1.f : 0.f;
        nad += (fabsf(v[j].w) < HALFB) ? 1.f : 0.f;
        mna = fminf(mna, fminf(v[j].x, v[j].y));
        mnb = fminf(mnb, fminf(v[j].z, v[j].w));
        mxa = fmaxf(mxa, fmaxf(v[j].x, v[j].y));
        mxb = fmaxf(mxb, fmaxf(v[j].z, v[j].w));
    }
    float g   = red8f((s0a + s0b) + (s0c + s0d));
    const float na0 = red8f((naa + nab) + (nac + nad));
    const float vmn = min8f(fminf(mna, mnb));
    const float vmx = max8f(fmaxf(mxa, mxb));

    const float t = fminf(fmaxf(g, -CAPB), CAPB);
    float lo  = vmn - (HALFB + CAPB);
    float hi  = vmx + (HALFB + CAPB);
    float lam = 0.f;
    float lam_p = 0.f, g_p = g;        // previous (lam, g) pair for secant

    for (int it = 0; it < 24; ++it) {
        if (__all(fabsf(g - t) <= 1e-4f)) break;   // wave-uniform exit
        if (g > t) lo = lam; else hi = lam;        // g decreasing in lam
        float ln;
        if (it == 0) {
            // Newton first step: true slope n_act(0) from the init sweep
            ln = (na0 > 0.f) ? lam + (g - t) * __builtin_amdgcn_rcpf(na0)
                             : 0.5f * (lo + hi);
        } else {
            // secant: slope from last two evals; exact on a shared PWL segment
            const float dg = g_p - g, dl = lam_p - lam;
            ln = (fabsf(dg) > 1e-9f)
                 ? lam + (g - t) * dl * __builtin_amdgcn_rcpf(dg)
                 : 0.5f * (lo + hi);
        }
        if (!(ln > lo && ln < hi)) ln = 0.5f * (lo + hi);   // bracket safeguard
        lam_p = lam; g_p = g;
        lam = ln;

        // g-only sweep: 3 ops/elem (sub, med3, add), one DPP reduce
        float ga = 0.f, gb = 0.f, gc = 0.f, gd = 0.f;
        #pragma unroll
        for (int j = 0; j < 4; ++j) {
            ga += clip05(v[j].x - lam); gb += clip05(v[j].y - lam);
            gc += clip05(v[j].z - lam); gd += clip05(v[j].w - lam);
        }
        g = red8f((ga + gb) + (gc + gd));
    }

    // one n_act sweep at the converged lam, then the exact closed form
    // (== reference's recompute over the active set)
    float pa = 0.f, pb = 0.f, pc = 0.f, pd = 0.f;
    #pragma unroll
    for (int j = 0; j < 4; ++j) {
        pa += (fabsf(v[j].x - lam) < HALFB) ? 1.f : 0.f;
        pb += (fabsf(v[j].y - lam) < HALFB) ? 1.f : 0.f;
        pc += (fabsf(v[j].z - lam) < HALFB) ? 1.f : 0.f;
        pd += (fabsf(v[j].w - lam) < HALFB) ? 1.f : 0.f;
    }
    const float na = red8f((pa + pb) + (pc + pd));
    const float lam_f = (na > 0.f) ? lam + (g - t) / na : lam;

    #pragma unroll
    for (int j = 0; j < 4; ++j) {
        po[j << 3] = make_float4(clip05(v[j].x - lam_f), clip05(v[j].y - lam_f),
                                 clip05(v[j].z - lam_f), clip05(v[j].w - lam_f));
    }
}

extern "C" void kernel_launch(void* const* d_in, const int* in_sizes, int n_in,
                              void* d_out, int out_size, void* d_ws, size_t ws_size,
                              hipStream_t stream) {
    const float* x = (const float*)d_in[0];
    float* out     = (float*)d_out;
    const int nrows = out_size / 128;             // 262144
    const int grid  = (nrows + 31) / 32;          // 8192 blocks, 32 rows each
    hipLaunchKernelGGL(proj_kernel, dim3(grid), dim3(256), 0, stream, x, out, nrows);
}

// Round 12
// 46.312 us; speedup vs baseline: 1.8977x; 1.8977x over previous
//
#include <hip/hip_runtime.h>

#define HALFB 0.5f
#define CAPB  0.1f

__device__ __forceinline__ float clip05(float z) {
    return fminf(fmaxf(z, -HALFB), HALFB);   // v_med3_f32
}

// 8-lane xor-reduce via DPP (pure VALU, no LDS pipe).
// 0xB1 = quad_perm xor1, 0x4E = quad_perm xor2, 0x141 = row_half_mirror
// (valid final stage: after xor1+xor2 each quad is uniform).
template <int CTRL>
__device__ __forceinline__ float dppf(float v) {
    return __int_as_float(__builtin_amdgcn_update_dpp(
        __float_as_int(v), __float_as_int(v), CTRL, 0xF, 0xF, false));
}
__device__ __forceinline__ float red8f(float v) {
    v += dppf<0xB1>(v); v += dppf<0x4E>(v); v += dppf<0x141>(v); return v;
}
__device__ __forceinline__ float min8f(float v) {
    v = fminf(v, dppf<0xB1>(v)); v = fminf(v, dppf<0x4E>(v));
    v = fminf(v, dppf<0x141>(v)); return v;
}
__device__ __forceinline__ float max8f(float v) {
    v = fmaxf(v, dppf<0xB1>(v)); v = fmaxf(v, dppf<0x141 == 0 ? 0x141 : 0x4E>(v));
    v = fmaxf(v, dppf<0x141>(v)); return v;
}

// Solve one 8-row group (8 lanes/row, 16 elems = 4 x float4 per lane,
// interleaved ownership). Newton math identical to round 10 (proven 45.4us,
// absmax 1.95e-3): per-iteration n_act slope, bracket safeguard, per-lane
// break, exact final division == reference's closed form.
__device__ __forceinline__ void solve8(const float4 (&v)[4], float4* __restrict__ po)
{
    float s0a = 0.f, s0b = 0.f, s0c = 0.f, s0d = 0.f;
    float naa = 0.f, nab = 0.f, nac = 0.f, nad = 0.f;
    float mna = 3.0e38f, mnb = 3.0e38f, mxa = -3.0e38f, mxb = -3.0e38f;
    #pragma unroll
    for (int j = 0; j < 4; ++j) {
        s0a += clip05(v[j].x); s0b += clip05(v[j].y);
        s0c += clip05(v[j].z); s0d += clip05(v[j].w);
        naa += (fabsf(v[j].x) < HALFB) ? 1.f : 0.f;
        nab += (fabsf(v[j].y) < HALFB) ? 1.f : 0.f;
        nac += (fabsf(v[j].z) < HALFB) ? 1.f : 0.f;
        nad += (fabsf(v[j].w) < HALFB) ? 1.f : 0.f;
        mna = fminf(mna, fminf(v[j].x, v[j].y));
        mnb = fminf(mnb, fminf(v[j].z, v[j].w));
        mxa = fmaxf(mxa, fmaxf(v[j].x, v[j].y));
        mxb = fmaxf(mxb, fmaxf(v[j].z, v[j].w));
    }
    float g  = red8f((s0a + s0b) + (s0c + s0d));
    float na = red8f((naa + nab) + (nac + nad));
    const float vmn = min8f(fminf(mna, mnb));
    const float vmx = max8f(fmaxf(mxa, mxb));

    const float t = fminf(fmaxf(g, -CAPB), CAPB);
    float lo  = vmn - (HALFB + CAPB);
    float hi  = vmx + (HALFB + CAPB);
    float lam = 0.f;

    for (int it = 0; it < 20; ++it) {
        if (fabsf(g - t) <= 1e-4f) break;     // final division heals residual
        if (g > t) lo = lam; else hi = lam;   // g decreasing in lam
        float ln;
        if (na > 0.f) {
            ln = lam + (g - t) * __builtin_amdgcn_rcpf(na);
            if (!(ln > lo && ln < hi)) ln = 0.5f * (lo + hi);
        } else {
            ln = 0.5f * (lo + hi);
        }
        if (ln == lam) break;
        lam = ln;

        float ga = 0.f, gb = 0.f, gc = 0.f, gd = 0.f;
        float pa = 0.f, pb = 0.f, pc = 0.f, pd = 0.f;
        #pragma unroll
        for (int j = 0; j < 4; ++j) {
            const float z0 = v[j].x - lam, z1 = v[j].y - lam;
            const float z2 = v[j].z - lam, z3 = v[j].w - lam;
            ga += clip05(z0); gb += clip05(z1);
            gc += clip05(z2); gd += clip05(z3);
            pa += (fabsf(z0) < HALFB) ? 1.f : 0.f;
            pb += (fabsf(z1) < HALFB) ? 1.f : 0.f;
            pc += (fabsf(z2) < HALFB) ? 1.f : 0.f;
            pd += (fabsf(z3) < HALFB) ? 1.f : 0.f;
        }
        g  = red8f((ga + gb) + (gc + gd));
        na = red8f((pa + pb) + (pc + pd));
    }

    const float lam_f = (na > 0.f) ? lam + (g - t) / na : lam;

    #pragma unroll
    for (int j = 0; j < 4; ++j) {
        po[j << 3] = make_float4(clip05(v[j].x - lam_f), clip05(v[j].y - lam_f),
                                 clip05(v[j].z - lam_f), clip05(v[j].w - lam_f));
    }
}

// 4096 blocks x 4 waves; each wave runs TWO 8-row groups. Both groups' loads
// (32 cache lines) issue up front: 2x memory-level parallelism per wave, and
// group 1's latency hides under group 0's ~1500-cycle solve. VGPR ~48-56
// (two 16-reg buffers) stays under the 64-VGPR occupancy cliff. 16 blocks/CU
// keeps tail balance (r9's 8/CU did not). Stores normal (nt proven harmful).
__global__ __launch_bounds__(256, 4) void proj_kernel(
    const float* __restrict__ x, float* __restrict__ out, int nrows)
{
    const int lane   = threadIdx.x & 63;
    const int q      = lane & 7;                   // eighth of row
    const int rsub   = lane >> 3;                  // row-in-group
    const int wid    = (blockIdx.x << 2) | (threadIdx.x >> 6);
    const int nwaves = gridDim.x << 2;             // 16384

    int row0 = (wid << 3) | rsub;                  // group 0
    int row1 = ((wid + nwaves) << 3) | rsub;       // group 1
    if (row0 >= nrows) row0 = nrows - 1;           // defensive; divides exactly
    if (row1 >= nrows) row1 = nrows - 1;

    const float4* __restrict__ px = (const float4*)x;
    float4*       __restrict__ po = (float4*)out;

    const float4* p0 = px + ((size_t)row0 << 5) + q;
    const float4* p1 = px + ((size_t)row1 << 5) + q;

    float4 v0[4], v1[4];
    #pragma unroll
    for (int j = 0; j < 4; ++j) v0[j] = p0[j << 3];   // stride 8 float4 = 128B
    #pragma unroll
    for (int j = 0; j < 4; ++j) v1[j] = p1[j << 3];   // in flight during solve 0

    solve8(v0, po + ((size_t)row0 << 5) + q);
    solve8(v1, po + ((size_t)row1 << 5) + q);
}

extern "C" void kernel_launch(void* const* d_in, const int* in_sizes, int n_in,
                              void* d_out, int out_size, void* d_ws, size_t ws_size,
                              hipStream_t stream) {
    const float* x = (const float*)d_in[0];
    float* out     = (float*)d_out;
    const int nrows = out_size / 128;                 // 262144
    // per block: 4 waves x 8 rows x 2 groups = 64 rows
    const int grid  = (nrows + 63) / 64;              // 4096
    hipLaunchKernelGGL(proj_kernel, dim3(grid), dim3(256), 0, stream, x, out, nrows);
}

// Round 13
// 45.769 us; speedup vs baseline: 1.9202x; 1.0119x over previous
//
#include <hip/hip_runtime.h>

#define HALFB 0.5f
#define CAPB  0.1f

__device__ __forceinline__ float clip05(float z) {
    return fminf(fmaxf(z, -HALFB), HALFB);   // v_med3_f32
}

// 8-lane xor-reduce via DPP (pure VALU, no LDS pipe).
// 0xB1 = quad_perm xor1, 0x4E = quad_perm xor2, 0x141 = row_half_mirror
// (valid final stage: after xor1+xor2 each quad is uniform). Proven in r10.
template <int CTRL>
__device__ __forceinline__ float dppf(float v) {
    return __int_as_float(__builtin_amdgcn_update_dpp(
        __float_as_int(v), __float_as_int(v), CTRL, 0xF, 0xF, false));
}
__device__ __forceinline__ float red8f(float v) {
    v += dppf<0xB1>(v); v += dppf<0x4E>(v); v += dppf<0x141>(v); return v;
}
__device__ __forceinline__ float min8f(float v) {
    v = fminf(v, dppf<0xB1>(v)); v = fminf(v, dppf<0x4E>(v));
    v = fminf(v, dppf<0x141>(v)); return v;
}
__device__ __forceinline__ float max8f(float v) {
    v = fmaxf(v, dppf<0xB1>(v)); v = fmaxf(v, dppf<0x4E>(v));
    v = fmaxf(v, dppf<0x141>(v)); return v;
}

// Wave-private LDS staging: every global access is lane-linear float4
// (64 lanes x 16B = 1KB contiguous per instruction — the copy-bench pattern,
// vs r10's 8 scattered 128B segments). LDS permutes linear <-> solver layout.
// Each wave touches only its own 4KB LDS slice: NO barriers; same-wave LDS
// ordering is handled by compiler lgkmcnt. Bank load is uniform (8 dwords/bank
// = b128 floor rate) for every LDS phase by construction.
// Solver: verbatim round 10 (proven 45.4us, absmax 1.95e-3).
__global__ __launch_bounds__(256, 4) void proj_kernel(
    const float* __restrict__ x, float* __restrict__ out, int nrows)
{
    __shared__ float4 tile[1024];            // 16 KB: 4 waves x 256 float4

    const int tid  = threadIdx.x;
    const int lane = tid & 63;
    const int w    = tid >> 6;
    const int q    = lane & 7;               // eighth of row
    const int rloc = lane >> 3;              // row within wave's 8-row slice

    // wave's 8 rows = 4KB = 256 float4, both globally and in LDS
    const size_t gbase = ((size_t)blockIdx.x << 10) + ((size_t)w << 8);
    const int    lbase = w << 8;

    const float4* __restrict__ pxl = (const float4*)x  + gbase;
    float4*       __restrict__ pol = (float4*)out      + gbase;

    // Phase 1: linear global loads (4 x 1KB contiguous per wave-instruction)
    float4 ld0 = pxl[lane];
    float4 ld1 = pxl[64  + lane];
    float4 ld2 = pxl[128 + lane];
    float4 ld3 = pxl[192 + lane];

    // Phase 2: stage to LDS linearly (uniform banks)
    tile[lbase + lane]       = ld0;
    tile[lbase + 64  + lane] = ld1;
    tile[lbase + 128 + lane] = ld2;
    tile[lbase + 192 + lane] = ld3;

    // Phase 3: read solver layout — lane q owns f4 {q, q+8, q+16, q+24} of row rloc
    float4 v[4];
    #pragma unroll
    for (int j = 0; j < 4; ++j)
        v[j] = tile[lbase + (rloc << 5) + (j << 3) + q];

    // ---- solver: verbatim round 10 ----
    float s0a = 0.f, s0b = 0.f, s0c = 0.f, s0d = 0.f;
    float naa = 0.f, nab = 0.f, nac = 0.f, nad = 0.f;
    float mna = 3.0e38f, mnb = 3.0e38f, mxa = -3.0e38f, mxb = -3.0e38f;
    #pragma unroll
    for (int j = 0; j < 4; ++j) {
        s0a += clip05(v[j].x); s0b += clip05(v[j].y);
        s0c += clip05(v[j].z); s0d += clip05(v[j].w);
        naa += (fabsf(v[j].x) < HALFB) ? 1.f : 0.f;
        nab += (fabsf(v[j].y) < HALFB) ? 1.f : 0.f;
        nac += (fabsf(v[j].z) < HALFB) ? 1.f : 0.f;
        nad += (fabsf(v[j].w) < HALFB) ? 1.f : 0.f;
        mna = fminf(mna, fminf(v[j].x, v[j].y));
        mnb = fminf(mnb, fminf(v[j].z, v[j].w));
        mxa = fmaxf(mxa, fmaxf(v[j].x, v[j].y));
        mxb = fmaxf(mxb, fmaxf(v[j].z, v[j].w));
    }
    float g  = red8f((s0a + s0b) + (s0c + s0d));
    float na = red8f((naa + nab) + (nac + nad));
    const float vmn = min8f(fminf(mna, mnb));
    const float vmx = max8f(fmaxf(mxa, mxb));

    const float t = fminf(fmaxf(g, -CAPB), CAPB);
    float lo  = vmn - (HALFB + CAPB);
    float hi  = vmx + (HALFB + CAPB);
    float lam = 0.f;

    for (int it = 0; it < 20; ++it) {
        if (fabsf(g - t) <= 1e-4f) break;     // final division heals residual
        if (g > t) lo = lam; else hi = lam;   // g decreasing in lam
        float ln;
        if (na > 0.f) {
            ln = lam + (g - t) * __builtin_amdgcn_rcpf(na);
            if (!(ln > lo && ln < hi)) ln = 0.5f * (lo + hi);
        } else {
            ln = 0.5f * (lo + hi);
        }
        if (ln == lam) break;
        lam = ln;

        float ga = 0.f, gb = 0.f, gc = 0.f, gd = 0.f;
        float pa = 0.f, pb = 0.f, pc = 0.f, pd = 0.f;
        #pragma unroll
        for (int j = 0; j < 4; ++j) {
            const float z0 = v[j].x - lam, z1 = v[j].y - lam;
            const float z2 = v[j].z - lam, z3 = v[j].w - lam;
            ga += clip05(z0); gb += clip05(z1);
            gc += clip05(z2); gd += clip05(z3);
            pa += (fabsf(z0) < HALFB) ? 1.f : 0.f;
            pb += (fabsf(z1) < HALFB) ? 1.f : 0.f;
            pc += (fabsf(z2) < HALFB) ? 1.f : 0.f;
            pd += (fabsf(z3) < HALFB) ? 1.f : 0.f;
        }
        g  = red8f((ga + gb) + (gc + gd));
        na = red8f((pa + pb) + (pc + pd));
    }

    const float lam_f = (na > 0.f) ? lam + (g - t) / na : lam;
    // ---- end solver ----

    // Phase 5: results back to LDS at solver layout (uniform banks)
    #pragma unroll
    for (int j = 0; j < 4; ++j)
        tile[lbase + (rloc << 5) + (j << 3) + q] =
            make_float4(clip05(v[j].x - lam_f), clip05(v[j].y - lam_f),
                        clip05(v[j].z - lam_f), clip05(v[j].w - lam_f));

    // Phase 6: linear copy out (4 x 1KB contiguous stores per wave-instruction)
    pol[lane]        = tile[lbase + lane];
    pol[64  + lane]  = tile[lbase + 64  + lane];
    pol[128 + lane]  = tile[lbase + 128 + lane];
    pol[192 + lane]  = tile[lbase + 192 + lane];
}

extern "C" void kernel_launch(void* const* d_in, const int* in_sizes, int n_in,
                              void* d_out, int out_size, void* d_ws, size_t ws_size,
                              hipStream_t stream) {
    const float* x = (const float*)d_in[0];
    float* out     = (float*)d_out;
    const int nrows = out_size / 128;             // 262144
    const int grid  = (nrows + 31) / 32;          // 8192 blocks x 32 rows
    hipLaunchKernelGGL(proj_kernel, dim3(grid), dim3(256), 0, stream, x, out, nrows);
}